// Round 1
// baseline (854.537 us; speedup 1.0000x reference)
//
#include <hip/hip_runtime.h>

#define Bn 8
#define Cn 64
#define Fn 256
#define Tn 512
#define FT (Fn*Tn)          // 131072
#define NPIX (Bn*Fn*Tn)     // 1048576
#define NTOT (Bn*Cn*Fn*Tn)  // 67108864

// ws float offsets
#define WS_MT    0               // [B*C*T] 262144  mean over F
#define WS_MF    262144          // [B*C*F] 131072  mean over T
#define WS_ZT    393216          // [B*C*T]
#define WS_ZFW   655360          // [B*C*F]  (zf * wc[c])
#define WS_WCAT  786432          // [64][128]: row k: [0:64]=Wb^T(c), [64:128]=W2^T(c)
#define WS_P     794624          // [64][24] prefix sums of wc2 over thresholds
#define WS_THR   796160          // [32]
#define WS_SUM   796192          // [64]
#define WS_SUMSQ 796256          // [64]
#define WS_SCALE 796320          // [64]
#define WS_SHIFT 796384          // [64]

// ---------------- K1: fused row/col means of each (b,c) slab ----------------
__global__ __launch_bounds__(256) void k1_sums(const float* __restrict__ x,
                                               float* __restrict__ ws) {
    const int slab = blockIdx.x;                 // b*64+c, 512 blocks
    const int wave = threadIdx.x >> 6, lane = threadIdx.x & 63;
    const float4* x4 = (const float4*)x + (size_t)slab * (FT / 4);
    __shared__ float lcs[4 * 512];
    float4 cs0 = {0.f,0.f,0.f,0.f}, cs1 = {0.f,0.f,0.f,0.f};
    for (int i = 0; i < 64; ++i) {
        const int f = wave * 64 + i;
        float4 v0 = x4[f * 128 + lane];
        float4 v1 = x4[f * 128 + 64 + lane];
        cs0.x += v0.x; cs0.y += v0.y; cs0.z += v0.z; cs0.w += v0.w;
        cs1.x += v1.x; cs1.y += v1.y; cs1.z += v1.z; cs1.w += v1.w;
        float r = (v0.x + v0.y) + (v0.z + v0.w) + (v1.x + v1.y) + (v1.z + v1.w);
        #pragma unroll
        for (int m = 1; m < 64; m <<= 1) r += __shfl_xor(r, m, 64);
        if (lane == 0) ws[WS_MF + slab * Fn + f] = r * (1.0f / Tn);
    }
    ((float4*)lcs)[wave * 128 + lane] = cs0;
    ((float4*)lcs)[wave * 128 + 64 + lane] = cs1;
    __syncthreads();
    for (int t = threadIdx.x; t < 512; t += 256) {
        float s = lcs[t] + lcs[512 + t] + lcs[1024 + t] + lcs[1536 + t];
        ws[WS_MT + slab * Tn + t] = s * (1.0f / Fn);
    }
}

// ---------------- K2: channel MLPs + weight folding / tables ----------------
__global__ __launch_bounds__(256) void k2_mlp_prep(
    const float* __restrict__ w1, const float* __restrict__ b1,
    const float* __restrict__ w2, const float* __restrict__ b2,
    const float* __restrict__ wc, const float* __restrict__ bc2,
    const float* __restrict__ wo, const float* __restrict__ wc2,
    float* __restrict__ ws) {
    const int blk = blockIdx.x;
    if (blk < 1536) {
        const int wave = threadIdx.x >> 6, c = threadIdx.x & 63;
        const bool is_t = (blk < 1024);
        float m; int b, l;
        if (is_t) {                       // zt positions: p = b*512 + t
            const int p = blk * 4 + wave;
            b = p >> 9; l = p & 511;
            m = ws[WS_MT + (b * 64 + c) * Tn + l];
        } else {                          // zf positions: p = b*256 + f
            const int p = (blk - 1024) * 4 + wave;
            b = p >> 8; l = p & 255;
            m = ws[WS_MF + (b * 64 + c) * Fn + l];
        }
        float acc = b2[c];
        #pragma unroll
        for (int o = 0; o < 5; ++o) {
            float v = w1[o * 64 + c] * m;
            #pragma unroll
            for (int mm = 1; mm < 64; mm <<= 1) v += __shfl_xor(v, mm, 64);
            const float h = fmaxf(v + b1[o], 0.0f);
            acc = fmaf(w2[c * 5 + o], h, acc);
        }
        const float sg = 1.0f / (1.0f + expf(-acc));
        if (is_t) ws[WS_ZT  + (b * 64 + c) * Tn + l] = sg;
        else      ws[WS_ZFW + (b * 64 + c) * Fn + l] = sg * wc[c];
    } else {
        const int tid = threadIdx.x;
        // folded weights, transposed: wcat[k][c] = wo1[c][k] + wo2[c][k]*bc2[k]; wcat[k][64+c] = wo2[c][k]
        for (int i = tid; i < 64 * 128; i += 256) {
            const int k = i >> 7, j = i & 127;
            float v;
            if (j < 64) v = wo[j * 128 + k] + wo[j * 128 + 64 + k] * bc2[k];
            else        v = wo[(j - 64) * 128 + 64 + k];
            ws[WS_WCAT + i] = v;
        }
        // P prefix sums over thresholds: P[c][K] = sum_{i<K} wc2[c][i]
        for (int c = tid; c < 64; c += 256) {
            float a = 0.f;
            ws[WS_P + c * 24 + 0] = 0.f;
            for (int K = 1; K <= 23; ++K) { a += wc2[c * 23 + K - 1]; ws[WS_P + c * 24 + K] = a; }
        }
        if (tid == 0) {  // exact replication of np.cumsum(np.arange(1,24)/300.0) -> fp32
            double a = 0.0;
            for (int i = 1; i <= 23; ++i) { a += (double)i / 300.0; ws[WS_THR + i - 1] = (float)a; }
            for (int i = 23; i < 32; ++i) ws[WS_THR + i] = 1e30f;
        }
        if (tid < 64) { ws[WS_SUM + tid] = 0.f; ws[WS_SUMSQ + tid] = 0.f; }
    }
}

// ---------------- K4: main fused pass: am -> level -> 64x128 matvec -> o ----------------
__global__ __launch_bounds__(256) void k4_main(
    const float* __restrict__ x, const float* __restrict__ wsc,
    const float* __restrict__ bc, const float* __restrict__ bo,
    float* __restrict__ out) {
    const int blk = blockIdx.x;           // 4096 blocks
    const int b = blk >> 9;
    const int rem = blk & 511;
    const int f = rem >> 1;
    const int t = ((rem & 1) << 8) + threadIdx.x;

    __shared__ float Pl[64 * 24];
    for (int i = threadIdx.x; i < 64 * 24; i += 256) Pl[i] = wsc[WS_P + i];
    __syncthreads();

    // attention map value (per pixel): dot over channels of zfw[b,c,f]*zt[b,c,t]
    const float* zfw = wsc + WS_ZFW + b * (Cn * Fn) + f;  // [c*256], block-uniform
    const float* zt  = wsc + WS_ZT  + b * (Cn * Tn) + t;  // [c*512], lane-coalesced
    float am = bc[0];
    #pragma unroll
    for (int c = 0; c < 64; ++c) am = fmaf(zfw[c * Fn], zt[c * Tn], am);

    int L = 0;
    #pragma unroll
    for (int i = 0; i < 23; ++i) L += (am > wsc[WS_THR + i]) ? 1 : 0;

    const int pix = b * (Cn * FT) + f * Tn + t;   // base at c=0
    const float* xp = x + pix;
    float* op = out + pix;
    const float* wcat = wsc + WS_WCAT;

    float acc[64];
    #pragma unroll
    for (int c = 0; c < 64; ++c) acc[c] = bo[c];

    float y = xp[0];
    for (int k = 0; k < 64; ++k) {
        const float ynext = (k < 63) ? xp[(k + 1) * FT] : 0.f;
        const float y2 = am * Pl[k * 24 + L] * y;
        const float* wr = wcat + k * 128;     // wave-uniform -> scalar loads
        #pragma unroll
        for (int c = 0; c < 64; ++c) {
            acc[c] = fmaf(wr[c], y, acc[c]);
            acc[c] = fmaf(wr[64 + c], y2, acc[c]);
        }
        y = ynext;
    }
    #pragma unroll
    for (int c = 0; c < 64; ++c) op[c * FT] = acc[c];
}

// ---------------- K5: per-channel BN statistics over o (in d_out) ----------------
__global__ __launch_bounds__(256) void k5_stats(const float* __restrict__ o,
                                                float* __restrict__ ws) {
    const int slab = blockIdx.x;      // b*64+c, 512 blocks
    const int c = slab & 63;
    const float4* o4 = (const float4*)o + (size_t)slab * (FT / 4);
    float s = 0.f, sq = 0.f;
    for (int i = threadIdx.x; i < FT / 4; i += 256) {
        float4 v = o4[i];
        s  += (v.x + v.y) + (v.z + v.w);
        sq += (v.x * v.x + v.y * v.y) + (v.z * v.z + v.w * v.w);
    }
    #pragma unroll
    for (int m = 1; m < 64; m <<= 1) { s += __shfl_xor(s, m, 64); sq += __shfl_xor(sq, m, 64); }
    __shared__ float ls[8];
    const int wave = threadIdx.x >> 6, lane = threadIdx.x & 63;
    if (lane == 0) { ls[wave] = s; ls[4 + wave] = sq; }
    __syncthreads();
    if (threadIdx.x == 0) {
        atomicAdd(&ws[WS_SUM + c],   ls[0] + ls[1] + ls[2] + ls[3]);
        atomicAdd(&ws[WS_SUMSQ + c], ls[4] + ls[5] + ls[6] + ls[7]);
    }
}

// ---------------- K6: fold BN stats into per-channel scale/shift ----------------
__global__ void k6_fin(const float* __restrict__ gamma, const float* __restrict__ beta,
                       float* __restrict__ ws) {
    const int c = threadIdx.x;
    if (c < 64) {
        const float n = (float)NPIX;
        const float mu = ws[WS_SUM + c] / n;
        const float var = ws[WS_SUMSQ + c] / n - mu * mu;
        const float sc = gamma[c] * rsqrtf(var + 1e-5f);
        ws[WS_SCALE + c] = sc;
        ws[WS_SHIFT + c] = beta[c] - mu * sc;
    }
}

// ---------------- K7: in-place normalize + ReLU ----------------
__global__ __launch_bounds__(256) void k7_norm(float* __restrict__ o,
                                               const float* __restrict__ ws) {
    const int n4 = NTOT / 4;                    // 16777216
    for (int i = blockIdx.x * 256 + threadIdx.x; i < n4; i += gridDim.x * 256) {
        const int c = (i >> 15) & 63;           // 32768 float4 per (b,c) slab
        const float sc = ws[WS_SCALE + c], sh = ws[WS_SHIFT + c];
        float4 v = ((float4*)o)[i];
        v.x = fmaxf(fmaf(v.x, sc, sh), 0.f);
        v.y = fmaxf(fmaf(v.y, sc, sh), 0.f);
        v.z = fmaxf(fmaf(v.z, sc, sh), 0.f);
        v.w = fmaxf(fmaf(v.w, sc, sh), 0.f);
        ((float4*)o)[i] = v;
    }
}

extern "C" void kernel_launch(void* const* d_in, const int* in_sizes, int n_in,
                              void* d_out, int out_size, void* d_ws, size_t ws_size,
                              hipStream_t stream) {
    const float* x     = (const float*)d_in[0];
    const float* w1    = (const float*)d_in[1];
    const float* b1    = (const float*)d_in[2];
    const float* w2    = (const float*)d_in[3];
    const float* b2    = (const float*)d_in[4];
    const float* wc    = (const float*)d_in[5];
    const float* bc    = (const float*)d_in[6];
    const float* wc2   = (const float*)d_in[7];
    const float* bc2   = (const float*)d_in[8];
    const float* wo    = (const float*)d_in[9];
    const float* bo    = (const float*)d_in[10];
    const float* gamma = (const float*)d_in[11];
    const float* beta  = (const float*)d_in[12];
    float* out = (float*)d_out;
    float* ws  = (float*)d_ws;

    k1_sums<<<512, 256, 0, stream>>>(x, ws);
    k2_mlp_prep<<<1537, 256, 0, stream>>>(w1, b1, w2, b2, wc, bc2, wo, wc2, ws);
    k4_main<<<4096, 256, 0, stream>>>(x, ws, bc, bo, out);
    k5_stats<<<512, 256, 0, stream>>>(out, ws);
    k6_fin<<<1, 64, 0, stream>>>(gamma, beta, ws);
    k7_norm<<<4096, 256, 0, stream>>>(out, ws);
}